// Round 1
// baseline (1753.030 us; speedup 1.0000x reference)
//
#include <hip/hip_runtime.h>

// QLlamaAttention on MI355X — round 1: correctness-first split-bf16 pipeline.
//
// Numerics: fake-quant boundaries amplify small errors (flip prob ~ eps/step,
// error = full step). Plain bf16 MFMA lands ~at the absmax threshold, so all
// GEMM-like contractions use split-bf16: x = hi + lo (two bf16), 3 MFMAs per
// fragment pair (hi*hi + hi*lo + lo*hi) -> ~2^-18 rel error, fp32-faithful.
// Quantization (group=32, mixed 4/6/8 bit) done in exact fp32 with rintf (RNE,
// matches jnp.round) and true division (matches g/s).
//
// Pipeline (all on `stream`):
//   quant(x) -> Xhl ; per W: quant(W) -> Whl ; gemm_split (128x128 tile,
//   16x16x32 bf16 MFMA, NT layout C[m,n]=sum_k A[m,k]B[n,k]) ; rope(Q,K) ->
//   hi/lo ; V epilogue writes transposed [b,h,d,s] hi/lo ; flash attention
//   (64q blocks, online softmax, P via per-wave LDS for C->A layout xform) ;
//   quant(o) ; final gemm -> d_out (fp32).
//
// Workspace: 224 MiB of d_ws (fully initialized every call; layout below).

typedef __attribute__((ext_vector_type(8))) short bfrag;   // 8 bf16 = 4 VGPR
typedef __attribute__((ext_vector_type(4))) float ffrag;   // MFMA C/D

#define MFMA16(a, b, c) __builtin_amdgcn_mfma_f32_16x16x32_bf16(a, b, c, 0, 0, 0)

__device__ __forceinline__ unsigned short f2bf(float f) {
  unsigned int u = __float_as_uint(f);
  u += 0x7fffu + ((u >> 16) & 1u);            // RNE
  return (unsigned short)(u >> 16);
}
__device__ __forceinline__ float bf2f(unsigned short h) {
  return __uint_as_float(((unsigned int)h) << 16);
}

// ---------------------------------------------------------------- quantize
// Fake-quant one 32-elem group per thread (cols: [0,2048)=4b, [2048,3072)=6b,
// [3072,4096)=8b), then split dq into bf16 hi/lo.
__global__ __launch_bounds__(256) void quant_split_k(
    const float* __restrict__ src, unsigned short* __restrict__ hi,
    unsigned short* __restrict__ lo, int ngroups) {
  int g = blockIdx.x * 256 + threadIdx.x;
  if (g >= ngroups) return;
  int gc = g & 127;                            // group index within a row
  float maxq = (gc < 64) ? 7.f : ((gc < 96) ? 31.f : 127.f);
  const float4* p = (const float4*)(src + (size_t)g * 32);
  float4 v[8];
  float amax = 0.f;
#pragma unroll
  for (int i = 0; i < 8; ++i) {
    v[i] = p[i];
    amax = fmaxf(amax, fmaxf(fmaxf(fabsf(v[i].x), fabsf(v[i].y)),
                             fmaxf(fabsf(v[i].z), fabsf(v[i].w))));
  }
  float s = amax / maxq;
  if (s == 0.f) s = 1.f;
  float lc = -maxq - 1.f;
  ushort4* ho = (ushort4*)(hi + (size_t)g * 32);
  ushort4* lo4 = (ushort4*)(lo + (size_t)g * 32);
#pragma unroll
  for (int i = 0; i < 8; ++i) {
    float xs[4] = {v[i].x, v[i].y, v[i].z, v[i].w};
    ushort4 hh, ll;
    unsigned short* hp = (unsigned short*)&hh;
    unsigned short* lp = (unsigned short*)&ll;
#pragma unroll
    for (int j = 0; j < 4; ++j) {
      float q = rintf(xs[j] / s);              // division to match reference
      q = fminf(fmaxf(q, lc), maxq);
      float dq = q * s;
      unsigned short h = f2bf(dq);
      hp[j] = h;
      lp[j] = f2bf(dq - bf2f(h));
    }
    ho[i] = hh;
    lo4[i] = ll;
  }
}

// ---------------------------------------------------------------- RoPE
// fp32 in (2048 x 4096 as b,s,h,d), rotate-half, write bf16 hi/lo.
__global__ __launch_bounds__(256) void rope_split_k(
    const float* __restrict__ src, unsigned short* __restrict__ hi,
    unsigned short* __restrict__ lo) {
  int idx = blockIdx.x * 256 + threadIdx.x;    // [0, 2048*32*64)
  int dp = idx & 63;
  int h = (idx >> 6) & 31;
  int tok = idx >> 11;
  int si = tok & 1023;
  size_t base = (size_t)tok * 4096 + h * 128 + dp;
  float x1 = src[base];
  float x2 = src[base + 64];
  float inv = powf(10000.f, -(float)dp * (1.f / 64.f));
  float ang = (float)si * inv;
  float sn, cs;
  sincosf(ang, &sn, &cs);                      // accurate range reduction
  float o1 = x1 * cs - x2 * sn;
  float o2 = x2 * cs + x1 * sn;
  unsigned short h1 = f2bf(o1), h2 = f2bf(o2);
  hi[base] = h1;
  lo[base] = f2bf(o1 - bf2f(h1));
  hi[base + 64] = h2;
  lo[base + 64] = f2bf(o2 - bf2f(h2));
}

// ---------------------------------------------------------------- GEMM
// C[m,n] = sum_k A[m,k]*B[n,k] (NT; B rows are W's n index, k contiguous).
// 128x128 tile, BK=32, 4 waves (2x2), each wave 4x4 16x16x32 frags, split
// bf16 -> 3 MFMAs per pair. LDS row stride 40 shorts (bank-uniform b128).
// mode 0: Cf[m*N+n] = acc (fp32). mode 1: V epilogue -> transposed hi/lo
// [ (b*32+h)*128 + d ]*1024 + s.
#define TS 40
__global__ __launch_bounds__(256, 2) void gemm_split_k(
    const unsigned short* __restrict__ Ah, const unsigned short* __restrict__ Al,
    const unsigned short* __restrict__ Bh, const unsigned short* __restrict__ Bl,
    float* __restrict__ Cf, unsigned short* __restrict__ Chi,
    unsigned short* __restrict__ Clo, int M, int N, int K, int mode) {
  __shared__ unsigned short sAh[128 * TS], sAl[128 * TS];
  __shared__ unsigned short sBh[128 * TS], sBl[128 * TS];
  int tid = threadIdx.x;
  int w = tid >> 6, lane = tid & 63, quad = lane >> 4, c = lane & 15;
  int wm = w >> 1, wn = w & 1;
  int bm = blockIdx.y * 128, bn = blockIdx.x * 128;
  int srow = tid >> 2;
  int scol = (tid & 3) * 8;
  ffrag acc[4][4] = {};
  for (int k0 = 0; k0 < K; k0 += 32) {
    __syncthreads();
    uint4 ra[2], rb2[2], rc2[2], rd2[2];
#pragma unroll
    for (int i = 0; i < 2; ++i) {
      size_t ga = (size_t)(bm + i * 64 + srow) * K + k0 + scol;
      size_t gb = (size_t)(bn + i * 64 + srow) * K + k0 + scol;
      ra[i] = *(const uint4*)(Ah + ga);
      rb2[i] = *(const uint4*)(Al + ga);
      rc2[i] = *(const uint4*)(Bh + gb);
      rd2[i] = *(const uint4*)(Bl + gb);
    }
#pragma unroll
    for (int i = 0; i < 2; ++i) {
      int off = (i * 64 + srow) * TS + scol;
      *(uint4*)&sAh[off] = ra[i];
      *(uint4*)&sAl[off] = rb2[i];
      *(uint4*)&sBh[off] = rc2[i];
      *(uint4*)&sBl[off] = rd2[i];
    }
    __syncthreads();
    bfrag ah[4], al[4], bh[4], bl[4];
#pragma unroll
    for (int i = 0; i < 4; ++i) {
      int ar = (wm * 64 + i * 16 + c) * TS + quad * 8;
      int br = (wn * 64 + i * 16 + c) * TS + quad * 8;
      ah[i] = *(const bfrag*)&sAh[ar];
      al[i] = *(const bfrag*)&sAl[ar];
      bh[i] = *(const bfrag*)&sBh[br];
      bl[i] = *(const bfrag*)&sBl[br];
    }
#pragma unroll
    for (int i = 0; i < 4; ++i)
#pragma unroll
      for (int j = 0; j < 4; ++j) {
        acc[i][j] = MFMA16(ah[i], bh[j], acc[i][j]);
        acc[i][j] = MFMA16(ah[i], bl[j], acc[i][j]);
        acc[i][j] = MFMA16(al[i], bh[j], acc[i][j]);
      }
  }
#pragma unroll
  for (int i = 0; i < 4; ++i)
#pragma unroll
    for (int j = 0; j < 4; ++j) {
      int m0 = bm + wm * 64 + i * 16 + quad * 4;
      int n = bn + wn * 64 + j * 16 + c;
#pragma unroll
      for (int r = 0; r < 4; ++r) {
        float val = acc[i][j][r];
        if (mode == 1) {
          int tok = m0 + r;
          int bb = tok >> 10, si = tok & 1023;
          int hh = n >> 7, d = n & 127;
          size_t o = ((size_t)(bb * 32 + hh) * 128 + d) * 1024 + si;
          unsigned short hv = f2bf(val);
          Chi[o] = hv;
          Clo[o] = f2bf(val - bf2f(hv));
        } else {
          Cf[(size_t)(m0 + r) * N + n] = val;
        }
      }
    }
}

// ---------------------------------------------------------------- attention
// grid (16 qblocks, 64 bh). Block = 64 queries, 4 waves x 16q. Q frags in
// registers (hi/lo); K and Vt fragments read directly from global (LLC
// resident, 16B per lane, 64B/row across quads). Online softmax per row
// (rows live in quad groups, reduce across the 16 c-lanes). P goes through
// per-wave LDS (fp32) for the C-layout -> A-layout transform, split hi/lo.
__global__ __launch_bounds__(256, 2) void attn_k(
    const unsigned short* __restrict__ Qh, const unsigned short* __restrict__ Ql,
    const unsigned short* __restrict__ Khg, const unsigned short* __restrict__ Klg,
    const unsigned short* __restrict__ Vhg, const unsigned short* __restrict__ Vlg,
    float* __restrict__ O) {
  __shared__ float sP[4][16 * 64];             // 16 KB, per-wave regions
  int qb = blockIdx.x, bh = blockIdx.y;
  int b = bh >> 5, h = bh & 31;
  int tid = threadIdx.x;
  int w = tid >> 6, lane = tid & 63, quad = lane >> 4, c = lane & 15;
  int q0 = qb * 64 + w * 16;
  bfrag aqh[4], aql[4];
  {
    const unsigned short* qr = Qh + (size_t)(b * 1024 + q0 + c) * 4096 + h * 128;
    const unsigned short* qrl = Ql + (size_t)(b * 1024 + q0 + c) * 4096 + h * 128;
#pragma unroll
    for (int kd = 0; kd < 4; ++kd) {
      aqh[kd] = *(const bfrag*)(qr + kd * 32 + quad * 8);
      aql[kd] = *(const bfrag*)(qrl + kd * 32 + quad * 8);
    }
  }
  ffrag oacc[8] = {};
  float mst[4], lst[4];
#pragma unroll
  for (int r = 0; r < 4; ++r) {
    mst[r] = -INFINITY;
    lst[r] = 0.f;
  }
  const float scale = 0.088388347648318447f;   // 1/sqrt(128)
  for (int kt = 0; kt <= qb; ++kt) {
    const unsigned short* kbase = Khg + (size_t)(b * 1024 + kt * 64) * 4096 + h * 128;
    const unsigned short* klbase = Klg + (size_t)(b * 1024 + kt * 64) * 4096 + h * 128;
    ffrag sf[4] = {};
#pragma unroll
    for (int kd = 0; kd < 4; ++kd) {
      bfrag kb[4], kl[4];
#pragma unroll
      for (int nb = 0; nb < 4; ++nb) {
        size_t roff = (size_t)(nb * 16 + c) * 4096 + kd * 32 + quad * 8;
        kb[nb] = *(const bfrag*)(kbase + roff);
        kl[nb] = *(const bfrag*)(klbase + roff);
      }
#pragma unroll
      for (int nb = 0; nb < 4; ++nb) {
        sf[nb] = MFMA16(aqh[kd], kb[nb], sf[nb]);
        sf[nb] = MFMA16(aqh[kd], kl[nb], sf[nb]);
        sf[nb] = MFMA16(aql[kd], kb[nb], sf[nb]);
      }
    }
    // scale + causal mask (diagonal tile only) + row max
    float rmax[4] = {-INFINITY, -INFINITY, -INFINITY, -INFINITY};
    bool diag = (kt == qb);
#pragma unroll
    for (int nb = 0; nb < 4; ++nb)
#pragma unroll
      for (int r = 0; r < 4; ++r) {
        float v = sf[nb][r] * scale;
        if (diag && (nb * 16 + c) > (w * 16 + quad * 4 + r)) v = -1e30f;
        sf[nb][r] = v;
        rmax[r] = fmaxf(rmax[r], v);
      }
#pragma unroll
    for (int mm = 1; mm < 16; mm <<= 1)
#pragma unroll
      for (int r = 0; r < 4; ++r)
        rmax[r] = fmaxf(rmax[r], __shfl_xor(rmax[r], mm, 64));
    float alpha[4], rsum[4];
#pragma unroll
    for (int r = 0; r < 4; ++r) {
      float mn = fmaxf(mst[r], rmax[r]);
      alpha[r] = __expf(mst[r] - mn);
      mst[r] = mn;
      rsum[r] = 0.f;
    }
#pragma unroll
    for (int nb = 0; nb < 4; ++nb)
#pragma unroll
      for (int r = 0; r < 4; ++r) {
        float p = __expf(sf[nb][r] - mst[r]);
        rsum[r] += p;
        sP[w][(quad * 4 + r) * 64 + nb * 16 + c] = p;
      }
#pragma unroll
    for (int mm = 1; mm < 16; mm <<= 1)
#pragma unroll
      for (int r = 0; r < 4; ++r) rsum[r] += __shfl_xor(rsum[r], mm, 64);
#pragma unroll
    for (int r = 0; r < 4; ++r) lst[r] = lst[r] * alpha[r] + rsum[r];
#pragma unroll
    for (int db = 0; db < 8; ++db)
#pragma unroll
      for (int r = 0; r < 4; ++r) oacc[db][r] *= alpha[r];
    __syncthreads();                           // sP visibility across lanes
    // PV: A = P (from LDS, split), B = Vt rows d, cols key
#pragma unroll
    for (int ks = 0; ks < 2; ++ks) {
      float4 u0 = *(const float4*)&sP[w][c * 64 + ks * 32 + quad * 8];
      float4 u1 = *(const float4*)&sP[w][c * 64 + ks * 32 + quad * 8 + 4];
      float pf[8] = {u0.x, u0.y, u0.z, u0.w, u1.x, u1.y, u1.z, u1.w};
      bfrag ph, pl;
#pragma unroll
      for (int j = 0; j < 8; ++j) {
        unsigned short hp = f2bf(pf[j]);
        ph[j] = (short)hp;
        pl[j] = (short)f2bf(pf[j] - bf2f(hp));
      }
#pragma unroll
      for (int db = 0; db < 8; ++db) {
        size_t voff = ((size_t)bh * 128 + db * 16 + c) * 1024 + kt * 64 + ks * 32 + quad * 8;
        bfrag vb = *(const bfrag*)(Vhg + voff);
        bfrag vl = *(const bfrag*)(Vlg + voff);
        oacc[db] = MFMA16(ph, vb, oacc[db]);
        oacc[db] = MFMA16(ph, vl, oacc[db]);
        oacc[db] = MFMA16(pl, vb, oacc[db]);
      }
    }
  }
  float invl[4];
#pragma unroll
  for (int r = 0; r < 4; ++r) invl[r] = 1.f / lst[r];
#pragma unroll
  for (int db = 0; db < 8; ++db)
#pragma unroll
    for (int r = 0; r < 4; ++r)
      O[(size_t)(b * 1024 + q0 + quad * 4 + r) * 4096 + h * 128 + db * 16 + c] =
          oacc[db][r] * invl[r];
}

// ---------------------------------------------------------------- launcher
extern "C" void kernel_launch(void* const* d_in, const int* in_sizes, int n_in,
                              void* d_out, int out_size, void* d_ws, size_t ws_size,
                              hipStream_t stream) {
  (void)in_sizes; (void)n_in; (void)out_size; (void)ws_size;
  const float* x = (const float*)d_in[0];
  const float* Wq = (const float*)d_in[1];
  const float* Wk = (const float*)d_in[2];
  const float* Wv = (const float*)d_in[3];
  const float* Wo = (const float*)d_in[4];
  float* out = (float*)d_out;
  char* ws = (char*)d_ws;
  const size_t MB = 1024ull * 1024ull;
  // workspace layout (224 MiB total)
  unsigned short* Xh = (unsigned short*)(ws);              // 16 MB (2048x4096 bf16)
  unsigned short* Xl = (unsigned short*)(ws + 16 * MB);    // 16 MB
  unsigned short* Wh = (unsigned short*)(ws + 32 * MB);    // 32 MB (4096x4096 bf16)
  unsigned short* Wl = (unsigned short*)(ws + 64 * MB);    // 32 MB
  float* S1 = (float*)(ws + 96 * MB);                      // 32 MB fp32 scratch
  unsigned short* Qh = (unsigned short*)(ws + 128 * MB);   // 16 MB
  unsigned short* Ql = (unsigned short*)(ws + 144 * MB);
  unsigned short* Kh = (unsigned short*)(ws + 160 * MB);
  unsigned short* Kl = (unsigned short*)(ws + 176 * MB);
  unsigned short* Vh = (unsigned short*)(ws + 192 * MB);   // transposed [b,h,d,s]
  unsigned short* Vl = (unsigned short*)(ws + 208 * MB);

  dim3 gg(32, 16), gb(256);
  quant_split_k<<<1024, 256, 0, stream>>>(x, Xh, Xl, 2048 * 128);
  // Q projection
  quant_split_k<<<2048, 256, 0, stream>>>(Wq, Wh, Wl, 4096 * 128);
  gemm_split_k<<<gg, gb, 0, stream>>>(Xh, Xl, Wh, Wl, S1, nullptr, nullptr,
                                      2048, 4096, 4096, 0);
  rope_split_k<<<16384, 256, 0, stream>>>(S1, Qh, Ql);
  // K projection
  quant_split_k<<<2048, 256, 0, stream>>>(Wk, Wh, Wl, 4096 * 128);
  gemm_split_k<<<gg, gb, 0, stream>>>(Xh, Xl, Wh, Wl, S1, nullptr, nullptr,
                                      2048, 4096, 4096, 0);
  rope_split_k<<<16384, 256, 0, stream>>>(S1, Kh, Kl);
  // V projection (epilogue writes transposed hi/lo)
  quant_split_k<<<2048, 256, 0, stream>>>(Wv, Wh, Wl, 4096 * 128);
  gemm_split_k<<<gg, gb, 0, stream>>>(Xh, Xl, Wh, Wl, nullptr, Vh, Vl,
                                      2048, 4096, 4096, 1);
  // attention -> o (fp32 into S1)
  attn_k<<<dim3(16, 64), 256, 0, stream>>>(Qh, Ql, Kh, Kl, Vh, Vl, S1);
  // output projection: quant(o) reuses X buffers
  quant_split_k<<<1024, 256, 0, stream>>>(S1, Xh, Xl, 2048 * 128);
  quant_split_k<<<2048, 256, 0, stream>>>(Wo, Wh, Wl, 4096 * 128);
  gemm_split_k<<<gg, gb, 0, stream>>>(Xh, Xl, Wh, Wl, out, nullptr, nullptr,
                                      2048, 4096, 4096, 0);
}

// Round 2
// 1483.668 us; speedup vs baseline: 1.1816x; 1.1816x over previous
//
#include <hip/hip_runtime.h>

// QLlamaAttention on MI355X — round 2: attn_k restructured (LDS-staged K/V
// shared across waves, shuffle-based P transpose, A=K/B=Q operand swap).
// GEMM / quant / rope kernels unchanged from round 1 (passed, absmax 0.031).
//
// Numerics: all contractions split-bf16 (x = hi + lo, 3 MFMAs per pair:
// hi*hi + hi*lo + lo*hi -> fp32-faithful). Quant in exact fp32, rintf (RNE),
// true division.

typedef __attribute__((ext_vector_type(8))) short bfrag;   // 8 bf16 = 4 VGPR
typedef __attribute__((ext_vector_type(4))) float ffrag;   // MFMA C/D

#define MFMA16(a, b, c) __builtin_amdgcn_mfma_f32_16x16x32_bf16(a, b, c, 0, 0, 0)

__device__ __forceinline__ unsigned short f2bf(float f) {
  unsigned int u = __float_as_uint(f);
  u += 0x7fffu + ((u >> 16) & 1u);            // RNE
  return (unsigned short)(u >> 16);
}
__device__ __forceinline__ float bf2f(unsigned short h) {
  return __uint_as_float(((unsigned int)h) << 16);
}

// ---------------------------------------------------------------- quantize
__global__ __launch_bounds__(256) void quant_split_k(
    const float* __restrict__ src, unsigned short* __restrict__ hi,
    unsigned short* __restrict__ lo, int ngroups) {
  int g = blockIdx.x * 256 + threadIdx.x;
  if (g >= ngroups) return;
  int gc = g & 127;                            // group index within a row
  float maxq = (gc < 64) ? 7.f : ((gc < 96) ? 31.f : 127.f);
  const float4* p = (const float4*)(src + (size_t)g * 32);
  float4 v[8];
  float amax = 0.f;
#pragma unroll
  for (int i = 0; i < 8; ++i) {
    v[i] = p[i];
    amax = fmaxf(amax, fmaxf(fmaxf(fabsf(v[i].x), fabsf(v[i].y)),
                             fmaxf(fabsf(v[i].z), fabsf(v[i].w))));
  }
  float s = amax / maxq;
  if (s == 0.f) s = 1.f;
  float lc = -maxq - 1.f;
  ushort4* ho = (ushort4*)(hi + (size_t)g * 32);
  ushort4* lo4 = (ushort4*)(lo + (size_t)g * 32);
#pragma unroll
  for (int i = 0; i < 8; ++i) {
    float xs[4] = {v[i].x, v[i].y, v[i].z, v[i].w};
    ushort4 hh, ll;
    unsigned short* hp = (unsigned short*)&hh;
    unsigned short* lp = (unsigned short*)&ll;
#pragma unroll
    for (int j = 0; j < 4; ++j) {
      float q = rintf(xs[j] / s);              // division to match reference
      q = fminf(fmaxf(q, lc), maxq);
      float dq = q * s;
      unsigned short h = f2bf(dq);
      hp[j] = h;
      lp[j] = f2bf(dq - bf2f(h));
    }
    ho[i] = hh;
    lo4[i] = ll;
  }
}

// ---------------------------------------------------------------- RoPE
__global__ __launch_bounds__(256) void rope_split_k(
    const float* __restrict__ src, unsigned short* __restrict__ hi,
    unsigned short* __restrict__ lo) {
  int idx = blockIdx.x * 256 + threadIdx.x;    // [0, 2048*32*64)
  int dp = idx & 63;
  int h = (idx >> 6) & 31;
  int tok = idx >> 11;
  int si = tok & 1023;
  size_t base = (size_t)tok * 4096 + h * 128 + dp;
  float x1 = src[base];
  float x2 = src[base + 64];
  float inv = powf(10000.f, -(float)dp * (1.f / 64.f));
  float ang = (float)si * inv;
  float sn, cs;
  sincosf(ang, &sn, &cs);
  float o1 = x1 * cs - x2 * sn;
  float o2 = x2 * cs + x1 * sn;
  unsigned short h1 = f2bf(o1), h2 = f2bf(o2);
  hi[base] = h1;
  lo[base] = f2bf(o1 - bf2f(h1));
  hi[base + 64] = h2;
  lo[base + 64] = f2bf(o2 - bf2f(h2));
}

// ---------------------------------------------------------------- GEMM
// (unchanged from round 1)
#define TS 40
__global__ __launch_bounds__(256, 2) void gemm_split_k(
    const unsigned short* __restrict__ Ah, const unsigned short* __restrict__ Al,
    const unsigned short* __restrict__ Bh, const unsigned short* __restrict__ Bl,
    float* __restrict__ Cf, unsigned short* __restrict__ Chi,
    unsigned short* __restrict__ Clo, int M, int N, int K, int mode) {
  __shared__ unsigned short sAh[128 * TS], sAl[128 * TS];
  __shared__ unsigned short sBh[128 * TS], sBl[128 * TS];
  int tid = threadIdx.x;
  int w = tid >> 6, lane = tid & 63, quad = lane >> 4, c = lane & 15;
  int wm = w >> 1, wn = w & 1;
  int bm = blockIdx.y * 128, bn = blockIdx.x * 128;
  int srow = tid >> 2;
  int scol = (tid & 3) * 8;
  ffrag acc[4][4] = {};
  for (int k0 = 0; k0 < K; k0 += 32) {
    __syncthreads();
    uint4 ra[2], rb2[2], rc2[2], rd2[2];
#pragma unroll
    for (int i = 0; i < 2; ++i) {
      size_t ga = (size_t)(bm + i * 64 + srow) * K + k0 + scol;
      size_t gb = (size_t)(bn + i * 64 + srow) * K + k0 + scol;
      ra[i] = *(const uint4*)(Ah + ga);
      rb2[i] = *(const uint4*)(Al + ga);
      rc2[i] = *(const uint4*)(Bh + gb);
      rd2[i] = *(const uint4*)(Bl + gb);
    }
#pragma unroll
    for (int i = 0; i < 2; ++i) {
      int off = (i * 64 + srow) * TS + scol;
      *(uint4*)&sAh[off] = ra[i];
      *(uint4*)&sAl[off] = rb2[i];
      *(uint4*)&sBh[off] = rc2[i];
      *(uint4*)&sBl[off] = rd2[i];
    }
    __syncthreads();
    bfrag ah[4], al[4], bh[4], bl[4];
#pragma unroll
    for (int i = 0; i < 4; ++i) {
      int ar = (wm * 64 + i * 16 + c) * TS + quad * 8;
      int br = (wn * 64 + i * 16 + c) * TS + quad * 8;
      ah[i] = *(const bfrag*)&sAh[ar];
      al[i] = *(const bfrag*)&sAl[ar];
      bh[i] = *(const bfrag*)&sBh[br];
      bl[i] = *(const bfrag*)&sBl[br];
    }
#pragma unroll
    for (int i = 0; i < 4; ++i)
#pragma unroll
      for (int j = 0; j < 4; ++j) {
        acc[i][j] = MFMA16(ah[i], bh[j], acc[i][j]);
        acc[i][j] = MFMA16(ah[i], bl[j], acc[i][j]);
        acc[i][j] = MFMA16(al[i], bh[j], acc[i][j]);
      }
  }
#pragma unroll
  for (int i = 0; i < 4; ++i)
#pragma unroll
    for (int j = 0; j < 4; ++j) {
      int m0 = bm + wm * 64 + i * 16 + quad * 4;
      int n = bn + wn * 64 + j * 16 + c;
#pragma unroll
      for (int r = 0; r < 4; ++r) {
        float val = acc[i][j][r];
        if (mode == 1) {
          int tok = m0 + r;
          int bb = tok >> 10, si = tok & 1023;
          int hh = n >> 7, d = n & 127;
          size_t o = ((size_t)(bb * 32 + hh) * 128 + d) * 1024 + si;
          unsigned short hv = f2bf(val);
          Chi[o] = hv;
          Clo[o] = f2bf(val - bf2f(hv));
        } else {
          Cf[(size_t)(m0 + r) * N + n] = val;
        }
      }
    }
}

// ---------------------------------------------------------------- attention
// Round 2: grid (16 qblocks, 64 bh), 4 waves x 16 q. Per kt tile (64 keys):
// cooperatively stage K (64x128) and Vt (128x64) hi/lo into LDS (XOR-swizzled
// 16B chunks: chunk' = c8 ^ row, keeps ds_read_b128 <=2-way conflicted).
// QK^T computed with A=K, B=Q so D[row=key, col=q]; softmax stats per
// q=lane&15 (2-shuffle butterfly over quad bits). P is moved to MFMA
// A-layout via 8 shuffles/frag (src lane = ((quad&1)*2+(j>=4))*16+c, frag
// select kb = sblk*2+(quad>>1)), exp'd in A-layout, split hi/lo. PV with
// B=Vt rows d. O lands as D[row=q, col=d]; alpha/l moved to reg-indexed
// rows via 4 shuffles. 64 KB LDS -> 2 blocks/CU.
__global__ __launch_bounds__(256, 2) void attn_k(
    const unsigned short* __restrict__ Qh, const unsigned short* __restrict__ Ql,
    const unsigned short* __restrict__ Khg, const unsigned short* __restrict__ Klg,
    const unsigned short* __restrict__ Vhg, const unsigned short* __restrict__ Vlg,
    float* __restrict__ O) {
  __shared__ unsigned short sKh[64 * 128], sKl[64 * 128];   // 16 KB each
  __shared__ unsigned short sVh[128 * 64], sVl[128 * 64];   // 16 KB each
  int qb = blockIdx.x, bh = blockIdx.y;
  int b = bh >> 5, h = bh & 31;
  int tid = threadIdx.x;
  int lane = tid & 63, w = tid >> 6, quad = lane >> 4, c = lane & 15;
  int q0 = qb * 64 + w * 16;
  // Q fragments (B operand: n = q = lane&15)
  bfrag bqh[4], bql[4];
  {
    const unsigned short* qr = Qh + ((size_t)(b * 1024 + q0 + c)) * 4096 + h * 128 + quad * 8;
    const unsigned short* qrl = Ql + ((size_t)(b * 1024 + q0 + c)) * 4096 + h * 128 + quad * 8;
#pragma unroll
    for (int kd = 0; kd < 4; ++kd) {
      bqh[kd] = *(const bfrag*)(qr + kd * 32);
      bql[kd] = *(const bfrag*)(qrl + kd * 32);
    }
  }
  int kr = tid >> 4, kc = tid & 15;            // K staging: 16 rows/round
  int vr = tid >> 3, vc = tid & 7;             // V staging: 32 rows/round
  ffrag oacc[8] = {};
  float m_q = -INFINITY, l_q = 0.f;
  const float scale = 0.088388347648318447f;   // 1/sqrt(128)
  const unsigned short* Kb = Khg + ((size_t)b * 1024) * 4096 + h * 128;
  const unsigned short* Klb = Klg + ((size_t)b * 1024) * 4096 + h * 128;
  const unsigned short* Vb = Vhg + ((size_t)bh * 128) * 1024;
  const unsigned short* Vlb = Vlg + ((size_t)bh * 128) * 1024;
  int sA = ((quad & 1) << 5) + c;              // P-transpose src lanes
  int sB = sA + 16;
  for (int kt = 0; kt <= qb; ++kt) {
    __syncthreads();
    {  // ---- stage K tile (64 x 128, hi+lo) ----
      uint4 th[4], tl[4];
#pragma unroll
      for (int rr = 0; rr < 4; ++rr) {
        size_t g = (size_t)(kt * 64 + rr * 16 + kr) * 4096 + kc * 8;
        th[rr] = *(const uint4*)(Kb + g);
        tl[rr] = *(const uint4*)(Klb + g);
      }
#pragma unroll
      for (int rr = 0; rr < 4; ++rr) {
        int row = rr * 16 + kr;
        int off = (row * 16 + (kc ^ (row & 15))) * 8;
        *(uint4*)&sKh[off] = th[rr];
        *(uint4*)&sKl[off] = tl[rr];
      }
    }
    {  // ---- stage Vt tile (128 x 64, hi+lo) ----
      uint4 th[4], tl[4];
#pragma unroll
      for (int rr = 0; rr < 4; ++rr) {
        size_t g = (size_t)(rr * 32 + vr) * 1024 + kt * 64 + vc * 8;
        th[rr] = *(const uint4*)(Vb + g);
        tl[rr] = *(const uint4*)(Vlb + g);
      }
#pragma unroll
      for (int rr = 0; rr < 4; ++rr) {
        int row = rr * 32 + vr;
        int off = (row * 8 + (vc ^ (row & 7))) * 8;
        *(uint4*)&sVh[off] = th[rr];
        *(uint4*)&sVl[off] = tl[rr];
      }
    }
    __syncthreads();
    // ---- S = K Q^T : D[row=key=quad*4+r, col=q=c] ----
    ffrag sf[4] = {};
#pragma unroll
    for (int kd = 0; kd < 4; ++kd) {
      bfrag ah[4], al[4];
#pragma unroll
      for (int kb = 0; kb < 4; ++kb) {
        int off = ((kb * 16 + c) * 16 + ((kd * 4 + quad) ^ c)) * 8;
        ah[kb] = *(const bfrag*)&sKh[off];
        al[kb] = *(const bfrag*)&sKl[off];
      }
#pragma unroll
      for (int kb = 0; kb < 4; ++kb) {
        sf[kb] = MFMA16(ah[kb], bqh[kd], sf[kb]);
        sf[kb] = MFMA16(ah[kb], bql[kd], sf[kb]);
        sf[kb] = MFMA16(al[kb], bqh[kd], sf[kb]);
      }
    }
    // ---- scale + causal mask + row max (per q = lane&15) ----
    float rmax = -INFINITY;
    bool diag = (kt == qb);
#pragma unroll
    for (int kb = 0; kb < 4; ++kb)
#pragma unroll
      for (int r = 0; r < 4; ++r) {
        float v = sf[kb][r] * scale;
        if (diag && (kb * 16 + quad * 4 + r) > (w * 16 + c)) v = -1e30f;
        sf[kb][r] = v;
        rmax = fmaxf(rmax, v);
      }
    rmax = fmaxf(rmax, __shfl_xor(rmax, 16, 64));
    rmax = fmaxf(rmax, __shfl_xor(rmax, 32, 64));
    float mn = fmaxf(m_q, rmax);
    float alpha = __expf(m_q - mn);
    m_q = mn;
    // ---- transpose S to A-layout (shuffles), exp, split hi/lo ----
    bfrag ph[2], pl[2];
    float rsum = 0.f;
#pragma unroll
    for (int sblk = 0; sblk < 2; ++sblk)
#pragma unroll
      for (int j = 0; j < 8; ++j) {
        int srclane = (j < 4) ? sA : sB;
        float v0 = __shfl(sf[sblk * 2 + 0][j & 3], srclane, 64);
        float v1 = __shfl(sf[sblk * 2 + 1][j & 3], srclane, 64);
        float v = (quad < 2) ? v0 : v1;
        float p = __expf(v - m_q);
        rsum += p;
        unsigned short hp = f2bf(p);
        ph[sblk][j] = (short)hp;
        pl[sblk][j] = (short)f2bf(p - bf2f(hp));
      }
    rsum += __shfl_xor(rsum, 16, 64);
    rsum += __shfl_xor(rsum, 32, 64);
    l_q = l_q * alpha + rsum;
    float al4[4];
#pragma unroll
    for (int r = 0; r < 4; ++r) al4[r] = __shfl(alpha, quad * 4 + r, 64);
#pragma unroll
    for (int db = 0; db < 8; ++db)
#pragma unroll
      for (int r = 0; r < 4; ++r) oacc[db][r] *= al4[r];
    // ---- O += P Vt : D[row=q=quad*4+r, col=d=c] ----
#pragma unroll
    for (int db = 0; db < 8; ++db) {
#pragma unroll
      for (int sblk = 0; sblk < 2; ++sblk) {
        int off = ((db * 16 + c) * 8 + ((sblk * 4 + quad) ^ (c & 7))) * 8;
        bfrag vh_ = *(const bfrag*)&sVh[off];
        bfrag vl_ = *(const bfrag*)&sVl[off];
        oacc[db] = MFMA16(ph[sblk], vh_, oacc[db]);
        oacc[db] = MFMA16(ph[sblk], vl_, oacc[db]);
        oacc[db] = MFMA16(pl[sblk], vh_, oacc[db]);
      }
    }
  }
  float invl[4];
#pragma unroll
  for (int r = 0; r < 4; ++r) invl[r] = 1.f / __shfl(l_q, quad * 4 + r, 64);
#pragma unroll
  for (int db = 0; db < 8; ++db)
#pragma unroll
    for (int r = 0; r < 4; ++r)
      O[((size_t)(b * 1024 + q0 + quad * 4 + r)) * 4096 + h * 128 + db * 16 + c] =
          oacc[db][r] * invl[r];
}

// ---------------------------------------------------------------- launcher
extern "C" void kernel_launch(void* const* d_in, const int* in_sizes, int n_in,
                              void* d_out, int out_size, void* d_ws, size_t ws_size,
                              hipStream_t stream) {
  (void)in_sizes; (void)n_in; (void)out_size; (void)ws_size;
  const float* x = (const float*)d_in[0];
  const float* Wq = (const float*)d_in[1];
  const float* Wk = (const float*)d_in[2];
  const float* Wv = (const float*)d_in[3];
  const float* Wo = (const float*)d_in[4];
  float* out = (float*)d_out;
  char* ws = (char*)d_ws;
  const size_t MB = 1024ull * 1024ull;
  unsigned short* Xh = (unsigned short*)(ws);              // 16 MB
  unsigned short* Xl = (unsigned short*)(ws + 16 * MB);    // 16 MB
  unsigned short* Wh = (unsigned short*)(ws + 32 * MB);    // 32 MB
  unsigned short* Wl = (unsigned short*)(ws + 64 * MB);    // 32 MB
  float* S1 = (float*)(ws + 96 * MB);                      // 32 MB fp32
  unsigned short* Qh = (unsigned short*)(ws + 128 * MB);
  unsigned short* Ql = (unsigned short*)(ws + 144 * MB);
  unsigned short* Kh = (unsigned short*)(ws + 160 * MB);
  unsigned short* Kl = (unsigned short*)(ws + 176 * MB);
  unsigned short* Vh = (unsigned short*)(ws + 192 * MB);   // transposed [b,h,d,s]
  unsigned short* Vl = (unsigned short*)(ws + 208 * MB);

  dim3 gg(32, 16), gb(256);
  quant_split_k<<<1024, 256, 0, stream>>>(x, Xh, Xl, 2048 * 128);
  quant_split_k<<<2048, 256, 0, stream>>>(Wq, Wh, Wl, 4096 * 128);
  gemm_split_k<<<gg, gb, 0, stream>>>(Xh, Xl, Wh, Wl, S1, nullptr, nullptr,
                                      2048, 4096, 4096, 0);
  rope_split_k<<<16384, 256, 0, stream>>>(S1, Qh, Ql);
  quant_split_k<<<2048, 256, 0, stream>>>(Wk, Wh, Wl, 4096 * 128);
  gemm_split_k<<<gg, gb, 0, stream>>>(Xh, Xl, Wh, Wl, S1, nullptr, nullptr,
                                      2048, 4096, 4096, 0);
  rope_split_k<<<16384, 256, 0, stream>>>(S1, Kh, Kl);
  quant_split_k<<<2048, 256, 0, stream>>>(Wv, Wh, Wl, 4096 * 128);
  gemm_split_k<<<gg, gb, 0, stream>>>(Xh, Xl, Wh, Wl, nullptr, Vh, Vl,
                                      2048, 4096, 4096, 1);
  attn_k<<<dim3(16, 64), 256, 0, stream>>>(Qh, Ql, Kh, Kl, Vh, Vl, S1);
  quant_split_k<<<1024, 256, 0, stream>>>(S1, Xh, Xl, 2048 * 128);
  quant_split_k<<<2048, 256, 0, stream>>>(Wo, Wh, Wl, 4096 * 128);
  gemm_split_k<<<gg, gb, 0, stream>>>(Xh, Xl, Wh, Wl, out, nullptr, nullptr,
                                      2048, 4096, 4096, 0);
}